// Round 6
// baseline (891.861 us; speedup 1.0000x reference)
//
#include <hip/hip_runtime.h>
#include <math.h>

#define I_  2049
#define M_  2
#define J_  2048
#define K_  8
#define N_  2
#define NITER 5
#define EPSF 1e-20f
#define INVJ (1.0/2048.0)
#define CHUNK 16   // i-chunk for k_vupd2: 129 y-blocks x 8 x-blocks = 1032 blocks

// ---------- static device-global state (n-innermost float2 layouts) ----------
__device__ float2 g_Xc[(size_t)I_*M_*J_];   // 67 MB: Xc(I,M,J) complex
__device__ float2 g_T2[I_*K_];              // T[i][k][n=2] as float2
__device__ float2 g_Told2[I_*K_];           // start-of-iter snapshot, both n
__device__ float2 g_V2[K_*J_];              // V[k][j][n=2] as float2
__device__ float2 g_W[I_*N_*M_];            // W[i][r][c]
__device__ float2 g_Wold[I_*N_*M_];         // iteration-start snapshot
__device__ float2 g_num2[K_*J_];            // numV[k][j][n=2]
__device__ float2 g_den2[K_*J_];            // denV[k][j][n=2]

// ---------- double-complex helpers (per-i 2x2 solve only) ----------
struct dcx { double x, y; };
__device__ __forceinline__ dcx cmul(dcx a, dcx b) { return {a.x*b.x - a.y*b.y, a.x*b.y + a.y*b.x}; }
__device__ __forceinline__ dcx cadd(dcx a, dcx b) { return {a.x + b.x, a.y + b.y}; }
__device__ __forceinline__ dcx csub(dcx a, dcx b) { return {a.x - b.x, a.y - b.y}; }
__device__ __forceinline__ dcx cneg(dcx a) { return {-a.x, -a.y}; }
__device__ __forceinline__ dcx cdiv(dcx a, dcx b) {
  double d = b.x*b.x + b.y*b.y;
  return {(a.x*b.x + a.y*b.y)/d, (a.y*b.x - a.x*b.y)/d};
}
__device__ __forceinline__ dcx csqrt_(dcx z) {   // principal branch, numpy-compatible
  double r = hypot(z.x, z.y);
  if (r == 0.0) return {0.0, 0.0};
  double t = sqrt(0.5*(r + fabs(z.x)));
  if (z.x >= 0.0) return {t, z.y/(2.0*t)};
  return {fabs(z.y)/(2.0*t), (z.y >= 0.0) ? t : -t};
}

// on-the-fly Yn: y = w0*x0 + w1*x1 (complex)
__device__ __forceinline__ float2 cyn(float2 w0, float2 w1, float2 x0, float2 x1) {
  float2 y;
  y.x = w0.x*x0.x - w0.y*x0.y + w1.x*x1.x - w1.y*x1.y;
  y.y = w0.x*x0.y + w0.y*x0.x + w1.x*x1.y + w1.y*x1.x;
  return y;
}

// ---------- setup: T<-T0, V<-V0, W=Wold=eye ----------
__global__ __launch_bounds__(256) void k_setup(const float* __restrict__ T0,
                                               const float* __restrict__ V0) {
  int idx = blockIdx.x*256 + threadIdx.x;
  if (idx < I_*K_) g_T2[idx] = ((const float2*)T0)[idx];   // (I,K,N) n-innermost
  if (idx < K_*J_) g_V2[idx] = ((const float2*)V0)[idx];   // (K,J,N) n-innermost
  if (idx < I_*N_*M_) {
    int r = (idx >> 1) & 1, c = idx & 1;
    float2 v = make_float2((r == c) ? 1.f : 0.f, 0.f);
    g_W[idx] = v;
    g_Wold[idx] = v;
  }
}

// ---------- transpose X(M,J,I,2) -> g_Xc(I,M,J) float2 ----------
__global__ __launch_bounds__(256) void k_transpose(const float* __restrict__ X) {
  __shared__ float sr[64][65];
  __shared__ float si[64][65];
  int it = blockIdx.x, jt = blockIdx.y, m = blockIdx.z;
  int lane = threadIdx.x & 63, row = threadIdx.x >> 6;
  int i0 = it*64, j0 = jt*64;
  const float2* X2 = (const float2*)X;   // (m*J + j)*I + i
  int gi = i0 + lane;
  if (gi < I_) {
    for (int jj = row; jj < 64; jj += 4) {
      float2 v = X2[(size_t)(m*J_ + j0 + jj)*I_ + gi];
      sr[lane][jj] = v.x; si[lane][jj] = v.y;
    }
  }
  __syncthreads();
  for (int ii = row; ii < 64; ii += 4) {
    int i = i0 + ii;
    if (i < I_) {
      g_Xc[((size_t)i*M_ + m)*J_ + (size_t)j0 + lane] =
          make_float2(sr[ii][lane], si[ii][lane]);
    }
  }
}

// ---------- fused T update, both n (block per i); blocks<256 zero num/den ----------
__global__ __launch_bounds__(256) void k_tupd2() {
  int i = blockIdx.x, t = threadIdx.x;
  if (i < 128)              ((float*)g_num2)[i*256 + t] = 0.f;
  else if (i < 256)         ((float*)g_den2)[(i - 128)*256 + t] = 0.f;
  float2 w00 = g_Wold[(size_t)i*4 + 0], w01 = g_Wold[(size_t)i*4 + 1];
  float2 w10 = g_Wold[(size_t)i*4 + 2], w11 = g_Wold[(size_t)i*4 + 3];
  float2 tk2[K_];
#pragma unroll
  for (int k = 0; k < K_; k++) tk2[k] = g_T2[(size_t)i*K_ + k];
  float aN0[K_], aD0[K_], aN1[K_], aD1[K_];
#pragma unroll
  for (int k = 0; k < K_; k++) { aN0[k]=0.f; aD0[k]=0.f; aN1[k]=0.f; aD1[k]=0.f; }
#pragma unroll
  for (int s = 0; s < J_/256; s++) {
    int j = t + 256*s;
    float2 vk2[K_];
#pragma unroll
    for (int k = 0; k < K_; k++) vk2[k] = g_V2[(size_t)k*J_ + j];
    float rn0 = 0.f, rn1 = 0.f;
#pragma unroll
    for (int k = 0; k < K_; k++) {
      rn0 = fmaf(tk2[k].x, vk2[k].x, rn0);
      rn1 = fmaf(tk2[k].y, vk2[k].y, rn1);
    }
    float2 x0 = g_Xc[((size_t)i*M_ + 0)*J_ + j];
    float2 x1 = g_Xc[((size_t)i*M_ + 1)*J_ + j];
    float2 y0 = cyn(w00, w01, x0, x1);
    float2 y1 = cyn(w10, w11, x0, x1);
    float p0  = (y0.x*y0.x + y0.y*y0.y) / (rn0*rn0 + EPSF);
    float p1  = (y1.x*y1.x + y1.y*y1.y) / (rn1*rn1 + EPSF);
    float rd0 = 1.f / rn0, rd1 = 1.f / rn1;
#pragma unroll
    for (int k = 0; k < K_; k++) {
      aN0[k] = fmaf(p0,  vk2[k].x, aN0[k]);
      aD0[k] = fmaf(rd0, vk2[k].x, aD0[k]);
      aN1[k] = fmaf(p1,  vk2[k].y, aN1[k]);
      aD1[k] = fmaf(rd1, vk2[k].y, aD1[k]);
    }
  }
#pragma unroll
  for (int k = 0; k < K_; k++)
    for (int off = 32; off; off >>= 1) {
      aN0[k] += __shfl_down(aN0[k], off);
      aD0[k] += __shfl_down(aD0[k], off);
      aN1[k] += __shfl_down(aN1[k], off);
      aD1[k] += __shfl_down(aD1[k], off);
    }
  __shared__ float red[4][32];
  int wave = t >> 6, lane = t & 63;
  if (lane == 0) {
#pragma unroll
    for (int k = 0; k < K_; k++) {
      red[wave][k]      = aN0[k];
      red[wave][8 + k]  = aD0[k];
      red[wave][16 + k] = aN1[k];
      red[wave][24 + k] = aD1[k];
    }
  }
  __syncthreads();
  if (t == 0) {
#pragma unroll
    for (int k = 0; k < K_; k++) {
      float n0 = red[0][k]    + red[1][k]    + red[2][k]    + red[3][k];
      float d0 = red[0][8+k]  + red[1][8+k]  + red[2][8+k]  + red[3][8+k];
      float n1 = red[0][16+k] + red[1][16+k] + red[2][16+k] + red[3][16+k];
      float d1 = red[0][24+k] + red[1][24+k] + red[2][24+k] + red[3][24+k];
      float2 tv = tk2[k];
      g_Told2[(size_t)i*K_ + k] = tv;
      g_T2[(size_t)i*K_ + k] = make_float2(tv.x * sqrtf(n0/d0), tv.y * sqrtf(n1/d1));
    }
  }
}

// ---------- fused V accumulation, both n; LDS-staged chunk state ----------
__global__ __launch_bounds__(256) void k_vupd2() {
  int t  = threadIdx.x;
  int j  = blockIdx.x*256 + t;
  int i0 = blockIdx.y*CHUNK;
  int ni = I_ - i0; if (ni > CHUNK) ni = CHUNK;

  __shared__ float2 sWold[CHUNK*4];   // 64  float2
  __shared__ float2 sTold[CHUNK*8];   // 128 float2
  __shared__ float2 sT[CHUNK*8];      // 128 float2
  // cooperative staging of 320 float2 (two rounds of 256 threads)
  for (int u = t; u < CHUNK*20; u += 256) {
    if (u < CHUNK*4) {
      int g = i0*4 + u;            if (g < I_*4) sWold[u] = g_Wold[g];
    } else if (u < CHUNK*12) {
      int g = i0*8 + (u - CHUNK*4); if (g < I_*8) sTold[u - CHUNK*4] = g_Told2[g];
    } else {
      int g = i0*8 + (u - CHUNK*12); if (g < I_*8) sT[u - CHUNK*12] = g_T2[g];
    }
  }
  __syncthreads();

  float2 vk2[K_];
#pragma unroll
  for (int k = 0; k < K_; k++) vk2[k] = g_V2[(size_t)k*J_ + j];
  float aN0[K_], aD0[K_], aN1[K_], aD1[K_];
#pragma unroll
  for (int k = 0; k < K_; k++) { aN0[k]=0.f; aD0[k]=0.f; aN1[k]=0.f; aD1[k]=0.f; }

#pragma unroll 4
  for (int ii = 0; ii < ni; ii++) {
    size_t ibase = (size_t)(i0 + ii)*M_*J_ + j;
    float2 x0 = g_Xc[ibase];
    float2 x1 = g_Xc[ibase + J_];
    float2 w00 = sWold[ii*4 + 0], w01 = sWold[ii*4 + 1];
    float2 w10 = sWold[ii*4 + 2], w11 = sWold[ii*4 + 3];
    float rn0 = 0.f, rn1 = 0.f;
#pragma unroll
    for (int k = 0; k < K_; k++) {
      float2 to = sTold[ii*8 + k];
      rn0 = fmaf(to.x, vk2[k].x, rn0);
      rn1 = fmaf(to.y, vk2[k].y, rn1);
    }
    float2 y0 = cyn(w00, w01, x0, x1);
    float2 y1 = cyn(w10, w11, x0, x1);
    float p0  = (y0.x*y0.x + y0.y*y0.y) / (rn0*rn0 + EPSF);
    float p1  = (y1.x*y1.x + y1.y*y1.y) / (rn1*rn1 + EPSF);
    float rd0 = 1.f / rn0, rd1 = 1.f / rn1;
#pragma unroll
    for (int k = 0; k < K_; k++) {
      float2 tn = sT[ii*8 + k];
      aN0[k] = fmaf(tn.x, p0,  aN0[k]);
      aD0[k] = fmaf(tn.x, rd0, aD0[k]);
      aN1[k] = fmaf(tn.y, p1,  aN1[k]);
      aD1[k] = fmaf(tn.y, rd1, aD1[k]);
    }
  }
  float* numF = (float*)g_num2;
  float* denF = (float*)g_den2;
#pragma unroll
  for (int k = 0; k < K_; k++) {
    atomicAdd(&numF[((size_t)k*J_ + j)*2 + 0], aN0[k]);
    atomicAdd(&numF[((size_t)k*J_ + j)*2 + 1], aN1[k]);
    atomicAdd(&denF[((size_t)k*J_ + j)*2 + 0], aD0[k]);
    atomicAdd(&denF[((size_t)k*J_ + j)*2 + 1], aD1[k]);
  }
}

__global__ __launch_bounds__(256) void k_vapply2() {
  int idx = blockIdx.x*256 + threadIdx.x;   // k*J + j
  float2 s = g_num2[idx], d = g_den2[idx], v = g_V2[idx];
  v.x *= sqrtf(s.x/d.x);
  v.y *= sqrtf(s.y/d.y);
  g_V2[idx] = v;
}

// ---------- fused D accumulation (both n) + sequential 2x2 solves + W write
// ---------- on last iteration (writeY) also emits Y = Wnew @ Xc into out ----------
__global__ __launch_bounds__(256) void k_dw2(float* __restrict__ out, int writeY, int cplx) {
  int i = blockIdx.x, t = threadIdx.x;
  float2 tk2[K_];
#pragma unroll
  for (int k = 0; k < K_; k++) tk2[k] = g_T2[(size_t)i*K_ + k];
  double acc[12];   // [n=0: D00r,D00i,D01r,D01i,D11r,D11i | n=1: same]
#pragma unroll
  for (int q = 0; q < 12; q++) acc[q] = 0.0;
#pragma unroll
  for (int s = 0; s < J_/256; s++) {
    int j = t + 256*s;
    float rn0 = 0.f, rn1 = 0.f;
#pragma unroll
    for (int k = 0; k < K_; k++) {
      float2 vk = g_V2[(size_t)k*J_ + j];
      rn0 = fmaf(tk2[k].x, vk.x, rn0);
      rn1 = fmaf(tk2[k].y, vk.y, rn1);
    }
    float2 x0 = g_Xc[((size_t)i*M_ + 0)*J_ + j];
    float2 x1 = g_Xc[((size_t)i*M_ + 1)*J_ + j];
    double a0 = x0.x, b0 = x0.y, a1 = x1.x, b1 = x1.y;
    double d00r = a0*a0 - b0*b0, d00i = 2.0*a0*b0;
    double d01r = a0*a1 - b0*b1, d01i = a0*b1 + a1*b0;
    double d11r = a1*a1 - b1*b1, d11i = 2.0*a1*b1;
    double inv0 = (double)(1.0f/rn0), inv1 = (double)(1.0f/rn1);  // f32 recip, ref-precision
    acc[0] += d00r*inv0; acc[1] += d00i*inv0;
    acc[2] += d01r*inv0; acc[3] += d01i*inv0;
    acc[4] += d11r*inv0; acc[5] += d11i*inv0;
    acc[6]  += d00r*inv1; acc[7]  += d00i*inv1;
    acc[8]  += d01r*inv1; acc[9]  += d01i*inv1;
    acc[10] += d11r*inv1; acc[11] += d11i*inv1;
  }
#pragma unroll
  for (int q = 0; q < 12; q++)
    for (int off = 32; off; off >>= 1) acc[q] += __shfl_down(acc[q], off);
  __shared__ double red[4][12];
  __shared__ float2 sW[4];
  int wave = t >> 6, lane = t & 63;
  if (lane == 0) {
#pragma unroll
    for (int q = 0; q < 12; q++) red[wave][q] = acc[q];
  }
  __syncthreads();
  if (t == 0) {
    double s_[12];
#pragma unroll
    for (int q = 0; q < 12; q++) s_[q] = red[0][q] + red[1][q] + red[2][q] + red[3][q];
    dcx Wl[2][2];
    Wl[0][0] = {g_W[(size_t)i*4+0].x, g_W[(size_t)i*4+0].y};
    Wl[0][1] = {g_W[(size_t)i*4+1].x, g_W[(size_t)i*4+1].y};
    Wl[1][0] = {g_W[(size_t)i*4+2].x, g_W[(size_t)i*4+2].y};
    Wl[1][1] = {g_W[(size_t)i*4+3].x, g_W[(size_t)i*4+3].y};
#pragma unroll
    for (int n = 0; n < N_; n++) {
      dcx D00 = {s_[6*n+0]*INVJ, s_[6*n+1]*INVJ};
      dcx D01 = {s_[6*n+2]*INVJ, s_[6*n+3]*INVJ};
      dcx D11 = {s_[6*n+4]*INVJ, s_[6*n+5]*INVJ};
      dcx WD00 = cadd(cmul(Wl[0][0], D00), cmul(Wl[0][1], D01));
      dcx WD01 = cadd(cmul(Wl[0][0], D01), cmul(Wl[0][1], D11));
      dcx WD10 = cadd(cmul(Wl[1][0], D00), cmul(Wl[1][1], D01));
      dcx WD11 = cadd(cmul(Wl[1][0], D01), cmul(Wl[1][1], D11));
      dcx det = csub(cmul(WD00, WD11), cmul(WD01, WD10));
      dcx b0, b1;
      if (n == 0) { b0 = cdiv(WD11, det);        b1 = cdiv(cneg(WD10), det); }
      else        { b0 = cdiv(cneg(WD01), det);  b1 = cdiv(WD00, det); }
      dcx nrm = cadd(cmul(cmul(b0, b0), D00), cmul(cmul(b1, b1), D11));
      dcx tcr = cmul(cmul(b0, b1), D01); tcr.x *= 2.0; tcr.y *= 2.0;
      nrm = cadd(nrm, tcr);
      dcx sq = csqrt_(nrm);
      Wl[0][n] = cdiv(b0, sq);   // reference writes COLUMN n
      Wl[1][n] = cdiv(b1, sq);
    }
    float2 o00 = make_float2((float)Wl[0][0].x, (float)Wl[0][0].y);
    float2 o01 = make_float2((float)Wl[0][1].x, (float)Wl[0][1].y);
    float2 o10 = make_float2((float)Wl[1][0].x, (float)Wl[1][0].y);
    float2 o11 = make_float2((float)Wl[1][1].x, (float)Wl[1][1].y);
    g_W[(size_t)i*4+0] = o00; g_W[(size_t)i*4+1] = o01;
    g_W[(size_t)i*4+2] = o10; g_W[(size_t)i*4+3] = o11;
    g_Wold[(size_t)i*4+0] = o00; g_Wold[(size_t)i*4+1] = o01;   // next iter's snapshot
    g_Wold[(size_t)i*4+2] = o10; g_Wold[(size_t)i*4+3] = o11;
    sW[0] = o00; sW[1] = o01; sW[2] = o10; sW[3] = o11;
  }
  __syncthreads();
  if (writeY) {
    float2 w00 = sW[0], w01 = sW[1], w10 = sW[2], w11 = sW[3];
    float2* out2 = (float2*)out;
#pragma unroll
    for (int s = 0; s < J_/256; s++) {
      int j = t + 256*s;
      float2 x0 = g_Xc[((size_t)i*M_ + 0)*J_ + j];
      float2 x1 = g_Xc[((size_t)i*M_ + 1)*J_ + j];
      float2 y0 = cyn(w00, w01, x0, x1);
      float2 y1 = cyn(w10, w11, x0, x1);
      if (cplx) {
        out2[((size_t)i*N_ + 0)*J_ + j] = y0;
        out2[((size_t)i*N_ + 1)*J_ + j] = y1;
      } else {      // float32(complex) == real part
        out[((size_t)i*N_ + 0)*J_ + j] = y0.x;
        out[((size_t)i*N_ + 1)*J_ + j] = y1.x;
      }
    }
  }
}

extern "C" void kernel_launch(void* const* d_in, const int* in_sizes, int n_in,
                              void* d_out, int out_size, void* d_ws, size_t ws_size,
                              hipStream_t stream) {
  const float* X  = (const float*)d_in[0];
  const float* T0 = (const float*)d_in[1];
  const float* V0 = (const float*)d_in[2];
  (void)d_ws; (void)ws_size;

  k_setup<<<(I_*K_ + 255)/256, 256, 0, stream>>>(T0, V0);
  k_transpose<<<dim3((I_ + 63)/64, J_/64, M_), 256, 0, stream>>>(X);

  int cplx = (out_size >= 2*I_*N_*J_) ? 1 : 0;
  for (int it = 0; it < NITER; it++) {
    int last = (it == NITER - 1) ? 1 : 0;
    k_tupd2<<<I_, 256, 0, stream>>>();
    k_vupd2<<<dim3(J_/256, (I_ + CHUNK - 1)/CHUNK), 256, 0, stream>>>();
    k_vapply2<<<K_*J_/256, 256, 0, stream>>>();
    k_dw2<<<I_, 256, 0, stream>>>((float*)d_out, last, cplx);
  }
}

// Round 7
// 646.681 us; speedup vs baseline: 1.3791x; 1.3791x over previous
//
#include <hip/hip_runtime.h>
#include <math.h>

#define I_  2049
#define M_  2
#define J_  2048
#define K_  8
#define N_  2
#define NITER 5
#define EPSF 1e-20f
#define INVJ (1.0/2048.0)
#define CHUNK 16
#define NCHUNK 129   // ceil(2049/16)

// ---------- static device-global state ----------
__device__ float4 g_Xc[(size_t)I_*J_];      // 67 MB: Xc(I,J,M) — both m of a j in one float4
__device__ float2 g_T2[I_*K_];              // T[i][k][n=2]
__device__ float2 g_Told2[I_*K_];           // start-of-iter snapshot
__device__ float2 g_V2[K_*J_];              // V[k][j][n=2]
__device__ float2 g_W[I_*N_*M_];            // W[i][r][c]
__device__ float2 g_Wold[I_*N_*M_];         // iteration-start snapshot
__device__ float2 g_pnum[(size_t)NCHUNK*K_*J_];  // 17 MB partials (n in float2)
__device__ float2 g_pden[(size_t)NCHUNK*K_*J_];

// ---------- double-complex helpers (per-i 2x2 solve only) ----------
struct dcx { double x, y; };
__device__ __forceinline__ dcx cmul(dcx a, dcx b) { return {a.x*b.x - a.y*b.y, a.x*b.y + a.y*b.x}; }
__device__ __forceinline__ dcx cadd(dcx a, dcx b) { return {a.x + b.x, a.y + b.y}; }
__device__ __forceinline__ dcx csub(dcx a, dcx b) { return {a.x - b.x, a.y - b.y}; }
__device__ __forceinline__ dcx cneg(dcx a) { return {-a.x, -a.y}; }
__device__ __forceinline__ dcx cdiv(dcx a, dcx b) {
  double d = b.x*b.x + b.y*b.y;
  return {(a.x*b.x + a.y*b.y)/d, (a.y*b.x - a.x*b.y)/d};
}
__device__ __forceinline__ dcx csqrt_(dcx z) {   // principal branch, numpy-compatible
  double r = hypot(z.x, z.y);
  if (r == 0.0) return {0.0, 0.0};
  double t = sqrt(0.5*(r + fabs(z.x)));
  if (z.x >= 0.0) return {t, z.y/(2.0*t)};
  return {fabs(z.y)/(2.0*t), (z.y >= 0.0) ? t : -t};
}

__device__ __forceinline__ float2 cyn(float2 w0, float2 w1, float2 x0, float2 x1) {
  float2 y;
  y.x = w0.x*x0.x - w0.y*x0.y + w1.x*x1.x - w1.y*x1.y;
  y.y = w0.x*x0.y + w0.y*x0.x + w1.x*x1.y + w1.y*x1.x;
  return y;
}

// ---------- setup: T<-T0, V<-V0, W=Wold=eye ----------
__global__ __launch_bounds__(256) void k_setup(const float* __restrict__ T0,
                                               const float* __restrict__ V0) {
  int idx = blockIdx.x*256 + threadIdx.x;
  if (idx < I_*K_) g_T2[idx] = ((const float2*)T0)[idx];
  if (idx < K_*J_) g_V2[idx] = ((const float2*)V0)[idx];
  if (idx < I_*N_*M_) {
    int r = (idx >> 1) & 1, c = idx & 1;
    float2 v = make_float2((r == c) ? 1.f : 0.f, 0.f);
    g_W[idx] = v;
    g_Wold[idx] = v;
  }
}

// ---------- transpose X(M,J,I,2) -> g_Xc(I,J,M) ----------
__global__ __launch_bounds__(256) void k_transpose(const float* __restrict__ X) {
  __shared__ float sr[64][65];
  __shared__ float si[64][65];
  int it = blockIdx.x, jt = blockIdx.y, m = blockIdx.z;
  int lane = threadIdx.x & 63, row = threadIdx.x >> 6;
  int i0 = it*64, j0 = jt*64;
  const float2* X2 = (const float2*)X;   // (m*J + j)*I + i
  int gi = i0 + lane;
  if (gi < I_) {
    for (int jj = row; jj < 64; jj += 4) {
      float2 v = X2[(size_t)(m*J_ + j0 + jj)*I_ + gi];
      sr[lane][jj] = v.x; si[lane][jj] = v.y;
    }
  }
  __syncthreads();
  float2* Xc2 = (float2*)g_Xc;   // (i*J + j)*2 + m
  for (int ii = row; ii < 64; ii += 4) {
    int i = i0 + ii;
    if (i < I_) {
      Xc2[((size_t)i*J_ + j0 + lane)*2 + m] = make_float2(sr[ii][lane], si[ii][lane]);
    }
  }
}

// ---------- fused T update, both n (block per i) ----------
__global__ __launch_bounds__(256) void k_tupd2() {
  int i = blockIdx.x, t = threadIdx.x;
  float2 w00 = g_Wold[(size_t)i*4 + 0], w01 = g_Wold[(size_t)i*4 + 1];
  float2 w10 = g_Wold[(size_t)i*4 + 2], w11 = g_Wold[(size_t)i*4 + 3];
  float2 tk2[K_];
#pragma unroll
  for (int k = 0; k < K_; k++) tk2[k] = g_T2[(size_t)i*K_ + k];
  float aN0[K_], aD0[K_], aN1[K_], aD1[K_];
#pragma unroll
  for (int k = 0; k < K_; k++) { aN0[k]=0.f; aD0[k]=0.f; aN1[k]=0.f; aD1[k]=0.f; }
#pragma unroll
  for (int s = 0; s < J_/256; s++) {
    int j = t + 256*s;
    float4 xv = g_Xc[(size_t)i*J_ + j];
    float2 vk2[K_];
#pragma unroll
    for (int k = 0; k < K_; k++) vk2[k] = g_V2[(size_t)k*J_ + j];
    float rn0 = 0.f, rn1 = 0.f;
#pragma unroll
    for (int k = 0; k < K_; k++) {
      rn0 = fmaf(tk2[k].x, vk2[k].x, rn0);
      rn1 = fmaf(tk2[k].y, vk2[k].y, rn1);
    }
    float2 x0 = make_float2(xv.x, xv.y);
    float2 x1 = make_float2(xv.z, xv.w);
    float2 y0 = cyn(w00, w01, x0, x1);
    float2 y1 = cyn(w10, w11, x0, x1);
    float p0  = (y0.x*y0.x + y0.y*y0.y) / (rn0*rn0 + EPSF);
    float p1  = (y1.x*y1.x + y1.y*y1.y) / (rn1*rn1 + EPSF);
    float rd0 = 1.f / rn0, rd1 = 1.f / rn1;
#pragma unroll
    for (int k = 0; k < K_; k++) {
      aN0[k] = fmaf(p0,  vk2[k].x, aN0[k]);
      aD0[k] = fmaf(rd0, vk2[k].x, aD0[k]);
      aN1[k] = fmaf(p1,  vk2[k].y, aN1[k]);
      aD1[k] = fmaf(rd1, vk2[k].y, aD1[k]);
    }
  }
#pragma unroll
  for (int k = 0; k < K_; k++)
    for (int off = 32; off; off >>= 1) {
      aN0[k] += __shfl_down(aN0[k], off);
      aD0[k] += __shfl_down(aD0[k], off);
      aN1[k] += __shfl_down(aN1[k], off);
      aD1[k] += __shfl_down(aD1[k], off);
    }
  __shared__ float red[4][32];
  int wave = t >> 6, lane = t & 63;
  if (lane == 0) {
#pragma unroll
    for (int k = 0; k < K_; k++) {
      red[wave][k]      = aN0[k];
      red[wave][8 + k]  = aD0[k];
      red[wave][16 + k] = aN1[k];
      red[wave][24 + k] = aD1[k];
    }
  }
  __syncthreads();
  if (t == 0) {
#pragma unroll
    for (int k = 0; k < K_; k++) {
      float n0 = red[0][k]    + red[1][k]    + red[2][k]    + red[3][k];
      float d0 = red[0][8+k]  + red[1][8+k]  + red[2][8+k]  + red[3][8+k];
      float n1 = red[0][16+k] + red[1][16+k] + red[2][16+k] + red[3][16+k];
      float d1 = red[0][24+k] + red[1][24+k] + red[2][24+k] + red[3][24+k];
      float2 tv = tk2[k];
      g_Told2[(size_t)i*K_ + k] = tv;
      g_T2[(size_t)i*K_ + k] = make_float2(tv.x * sqrtf(n0/d0), tv.y * sqrtf(n1/d1));
    }
  }
}

// ---------- V partial accumulation, both n; NO atomics — per-chunk partial write ----------
__global__ __launch_bounds__(256) void k_vupd2() {
  int t  = threadIdx.x;
  int j  = blockIdx.x*256 + t;
  int c  = blockIdx.y;
  int i0 = c*CHUNK;
  int ni = I_ - i0; if (ni > CHUNK) ni = CHUNK;

  __shared__ float2 sWold[CHUNK*4];
  __shared__ float2 sTold[CHUNK*8];
  __shared__ float2 sT[CHUNK*8];
  for (int u = t; u < CHUNK*20; u += 256) {
    if (u < CHUNK*4) {
      int g = i0*4 + u;              if (g < I_*4) sWold[u] = g_Wold[g];
    } else if (u < CHUNK*12) {
      int g = i0*8 + (u - CHUNK*4);  if (g < I_*8) sTold[u - CHUNK*4] = g_Told2[g];
    } else {
      int g = i0*8 + (u - CHUNK*12); if (g < I_*8) sT[u - CHUNK*12] = g_T2[g];
    }
  }
  __syncthreads();

  float2 vk2[K_];
#pragma unroll
  for (int k = 0; k < K_; k++) vk2[k] = g_V2[(size_t)k*J_ + j];
  float aN0[K_], aD0[K_], aN1[K_], aD1[K_];
#pragma unroll
  for (int k = 0; k < K_; k++) { aN0[k]=0.f; aD0[k]=0.f; aN1[k]=0.f; aD1[k]=0.f; }

  auto body = [&](int ii, float4 xv) {
    float2 x0 = make_float2(xv.x, xv.y);
    float2 x1 = make_float2(xv.z, xv.w);
    float2 w00 = sWold[ii*4 + 0], w01 = sWold[ii*4 + 1];
    float2 w10 = sWold[ii*4 + 2], w11 = sWold[ii*4 + 3];
    float rn0 = 0.f, rn1 = 0.f;
#pragma unroll
    for (int k = 0; k < K_; k++) {
      float2 to = sTold[ii*8 + k];
      rn0 = fmaf(to.x, vk2[k].x, rn0);
      rn1 = fmaf(to.y, vk2[k].y, rn1);
    }
    float2 y0 = cyn(w00, w01, x0, x1);
    float2 y1 = cyn(w10, w11, x0, x1);
    float p0  = (y0.x*y0.x + y0.y*y0.y) / (rn0*rn0 + EPSF);
    float p1  = (y1.x*y1.x + y1.y*y1.y) / (rn1*rn1 + EPSF);
    float rd0 = 1.f / rn0, rd1 = 1.f / rn1;
#pragma unroll
    for (int k = 0; k < K_; k++) {
      float2 tn = sT[ii*8 + k];
      aN0[k] = fmaf(tn.x, p0,  aN0[k]);
      aD0[k] = fmaf(tn.x, rd0, aD0[k]);
      aN1[k] = fmaf(tn.y, p1,  aN1[k]);
      aD1[k] = fmaf(tn.y, rd1, aD1[k]);
    }
  };

  int ii = 0;
  for (; ii + 8 <= ni; ii += 8) {
    float4 xv[8];
#pragma unroll
    for (int u = 0; u < 8; u++) xv[u] = g_Xc[(size_t)(i0 + ii + u)*J_ + j];
#pragma unroll
    for (int u = 0; u < 8; u++) body(ii + u, xv[u]);
  }
  for (; ii < ni; ii++) {
    float4 xv = g_Xc[(size_t)(i0 + ii)*J_ + j];
    body(ii, xv);
  }

  size_t base = (size_t)c*(K_*J_);
#pragma unroll
  for (int k = 0; k < K_; k++) {
    g_pnum[base + (size_t)k*J_ + j] = make_float2(aN0[k], aN1[k]);
    g_pden[base + (size_t)k*J_ + j] = make_float2(aD0[k], aD1[k]);
  }
}

// ---------- chunk-reduce partials + apply V *= sqrt(num/den) ----------
__global__ __launch_bounds__(256) void k_vapply2() {
  int t = threadIdx.x;
  int idx = blockIdx.x*32 + (t & 31);       // kj index, 512 blocks x 32
  int slice = t >> 5;                       // 8 c-slices of 17
  int c0 = slice*17, c1 = c0 + 17; if (c1 > NCHUNK) c1 = NCHUNK;
  float2 sn = make_float2(0.f, 0.f), sd = make_float2(0.f, 0.f);
#pragma unroll 4
  for (int c = c0; c < c1; c++) {
    float2 a = g_pnum[(size_t)c*(K_*J_) + idx];
    float2 b = g_pden[(size_t)c*(K_*J_) + idx];
    sn.x += a.x; sn.y += a.y; sd.x += b.x; sd.y += b.y;
  }
  __shared__ float2 rN[8][32], rD[8][32];
  rN[slice][t & 31] = sn; rD[slice][t & 31] = sd;
  __syncthreads();
  if (t < 32) {
    float2 n = rN[0][t], d = rD[0][t];
#pragma unroll
    for (int s = 1; s < 8; s++) {
      n.x += rN[s][t].x; n.y += rN[s][t].y;
      d.x += rD[s][t].x; d.y += rD[s][t].y;
    }
    float2 v = g_V2[idx];
    v.x *= sqrtf(n.x/d.x);
    v.y *= sqrtf(n.y/d.y);
    g_V2[idx] = v;
  }
}

// ---------- fused D accumulation + 2x2 solves + W write (+Y on last iter) ----------
__global__ __launch_bounds__(256) void k_dw2(float* __restrict__ out, int writeY, int cplx) {
  int i = blockIdx.x, t = threadIdx.x;
  float2 tk2[K_];
#pragma unroll
  for (int k = 0; k < K_; k++) tk2[k] = g_T2[(size_t)i*K_ + k];
  double acc[12];
#pragma unroll
  for (int q = 0; q < 12; q++) acc[q] = 0.0;
#pragma unroll
  for (int s = 0; s < J_/256; s++) {
    int j = t + 256*s;
    float rn0 = 0.f, rn1 = 0.f;
#pragma unroll
    for (int k = 0; k < K_; k++) {
      float2 vk = g_V2[(size_t)k*J_ + j];
      rn0 = fmaf(tk2[k].x, vk.x, rn0);
      rn1 = fmaf(tk2[k].y, vk.y, rn1);
    }
    float4 xv = g_Xc[(size_t)i*J_ + j];
    double a0 = xv.x, b0 = xv.y, a1 = xv.z, b1 = xv.w;
    double d00r = a0*a0 - b0*b0, d00i = 2.0*a0*b0;
    double d01r = a0*a1 - b0*b1, d01i = a0*b1 + a1*b0;
    double d11r = a1*a1 - b1*b1, d11i = 2.0*a1*b1;
    double inv0 = (double)(1.0f/rn0), inv1 = (double)(1.0f/rn1);
    acc[0] += d00r*inv0; acc[1] += d00i*inv0;
    acc[2] += d01r*inv0; acc[3] += d01i*inv0;
    acc[4] += d11r*inv0; acc[5] += d11i*inv0;
    acc[6]  += d00r*inv1; acc[7]  += d00i*inv1;
    acc[8]  += d01r*inv1; acc[9]  += d01i*inv1;
    acc[10] += d11r*inv1; acc[11] += d11i*inv1;
  }
#pragma unroll
  for (int q = 0; q < 12; q++)
    for (int off = 32; off; off >>= 1) acc[q] += __shfl_down(acc[q], off);
  __shared__ double red[4][12];
  __shared__ float2 sW[4];
  int wave = t >> 6, lane = t & 63;
  if (lane == 0) {
#pragma unroll
    for (int q = 0; q < 12; q++) red[wave][q] = acc[q];
  }
  __syncthreads();
  if (t == 0) {
    double s_[12];
#pragma unroll
    for (int q = 0; q < 12; q++) s_[q] = red[0][q] + red[1][q] + red[2][q] + red[3][q];
    dcx Wl[2][2];
    Wl[0][0] = {g_W[(size_t)i*4+0].x, g_W[(size_t)i*4+0].y};
    Wl[0][1] = {g_W[(size_t)i*4+1].x, g_W[(size_t)i*4+1].y};
    Wl[1][0] = {g_W[(size_t)i*4+2].x, g_W[(size_t)i*4+2].y};
    Wl[1][1] = {g_W[(size_t)i*4+3].x, g_W[(size_t)i*4+3].y};
#pragma unroll
    for (int n = 0; n < N_; n++) {
      dcx D00 = {s_[6*n+0]*INVJ, s_[6*n+1]*INVJ};
      dcx D01 = {s_[6*n+2]*INVJ, s_[6*n+3]*INVJ};
      dcx D11 = {s_[6*n+4]*INVJ, s_[6*n+5]*INVJ};
      dcx WD00 = cadd(cmul(Wl[0][0], D00), cmul(Wl[0][1], D01));
      dcx WD01 = cadd(cmul(Wl[0][0], D01), cmul(Wl[0][1], D11));
      dcx WD10 = cadd(cmul(Wl[1][0], D00), cmul(Wl[1][1], D01));
      dcx WD11 = cadd(cmul(Wl[1][0], D01), cmul(Wl[1][1], D11));
      dcx det = csub(cmul(WD00, WD11), cmul(WD01, WD10));
      dcx b0, b1;
      if (n == 0) { b0 = cdiv(WD11, det);        b1 = cdiv(cneg(WD10), det); }
      else        { b0 = cdiv(cneg(WD01), det);  b1 = cdiv(WD00, det); }
      dcx nrm = cadd(cmul(cmul(b0, b0), D00), cmul(cmul(b1, b1), D11));
      dcx tcr = cmul(cmul(b0, b1), D01); tcr.x *= 2.0; tcr.y *= 2.0;
      nrm = cadd(nrm, tcr);
      dcx sq = csqrt_(nrm);
      Wl[0][n] = cdiv(b0, sq);
      Wl[1][n] = cdiv(b1, sq);
    }
    float2 o00 = make_float2((float)Wl[0][0].x, (float)Wl[0][0].y);
    float2 o01 = make_float2((float)Wl[0][1].x, (float)Wl[0][1].y);
    float2 o10 = make_float2((float)Wl[1][0].x, (float)Wl[1][0].y);
    float2 o11 = make_float2((float)Wl[1][1].x, (float)Wl[1][1].y);
    g_W[(size_t)i*4+0] = o00; g_W[(size_t)i*4+1] = o01;
    g_W[(size_t)i*4+2] = o10; g_W[(size_t)i*4+3] = o11;
    g_Wold[(size_t)i*4+0] = o00; g_Wold[(size_t)i*4+1] = o01;
    g_Wold[(size_t)i*4+2] = o10; g_Wold[(size_t)i*4+3] = o11;
    sW[0] = o00; sW[1] = o01; sW[2] = o10; sW[3] = o11;
  }
  __syncthreads();
  if (writeY) {
    float2 w00 = sW[0], w01 = sW[1], w10 = sW[2], w11 = sW[3];
    float2* out2 = (float2*)out;
#pragma unroll
    for (int s = 0; s < J_/256; s++) {
      int j = t + 256*s;
      float4 xv = g_Xc[(size_t)i*J_ + j];
      float2 x0 = make_float2(xv.x, xv.y);
      float2 x1 = make_float2(xv.z, xv.w);
      float2 y0 = cyn(w00, w01, x0, x1);
      float2 y1 = cyn(w10, w11, x0, x1);
      if (cplx) {
        out2[((size_t)i*N_ + 0)*J_ + j] = y0;
        out2[((size_t)i*N_ + 1)*J_ + j] = y1;
      } else {      // float32(complex) == real part
        out[((size_t)i*N_ + 0)*J_ + j] = y0.x;
        out[((size_t)i*N_ + 1)*J_ + j] = y1.x;
      }
    }
  }
}

extern "C" void kernel_launch(void* const* d_in, const int* in_sizes, int n_in,
                              void* d_out, int out_size, void* d_ws, size_t ws_size,
                              hipStream_t stream) {
  const float* X  = (const float*)d_in[0];
  const float* T0 = (const float*)d_in[1];
  const float* V0 = (const float*)d_in[2];
  (void)d_ws; (void)ws_size;

  k_setup<<<(I_*K_ + 255)/256, 256, 0, stream>>>(T0, V0);
  k_transpose<<<dim3((I_ + 63)/64, J_/64, M_), 256, 0, stream>>>(X);

  int cplx = (out_size >= 2*I_*N_*J_) ? 1 : 0;
  for (int it = 0; it < NITER; it++) {
    int last = (it == NITER - 1) ? 1 : 0;
    k_tupd2<<<I_, 256, 0, stream>>>();
    k_vupd2<<<dim3(J_/256, NCHUNK), 256, 0, stream>>>();
    k_vapply2<<<K_*J_/32, 256, 0, stream>>>();
    k_dw2<<<I_, 256, 0, stream>>>((float*)d_out, last, cplx);
  }
}